// Round 1
// baseline (822.478 us; speedup 1.0000x reference)
//
#include <hip/hip_runtime.h>

// CapsuleLayer dynamic routing on MI355X.
// x: [128, 2048, 8] f32, W: [2048, 32, 8, 16] f32, out v: [128, 32, 16] f32.
// Strategy: recompute u_hat per pass in registers (never materialize 537MB),
// 3 heavy passes + 3 squash kernels. iter2 uses dot(u, v0+v1) fusion.

constexpr int NC = 2048;   // in_caps
constexpr int OC = 32;     // out_caps
constexpr int OD = 16;     // out_dim

// Heavy pass kernel.
// grid = 512 blocks: bt(16) x nt(32). block = 256 threads.
// Block covers b in [bt*8, bt*8+8), n in [nt*64, nt*64+64) via 16 k-steps of 4 n.
// Pair = (b, n) handled by 8 lanes; lane l owns o in {l, l+8, l+16, l+24}, all 16 d.
// W[4 n] staged in LDS each k-step, XOR-swizzled: unit (r, c) stored at c ^ (r&7).
template<bool FIRST>
__global__ __launch_bounds__(256, 2)
void caps_pass(const float* __restrict__ xg, const float* __restrict__ Wg,
               const float* __restrict__ vin, float* __restrict__ sout)
{
    __shared__ float4 Wl[4 * 32 * 32];   // [r:128 rows][c:32 float4 cols], swizzled

    const int tid = threadIdx.x;
    const int bt  = blockIdx.x >> 5;     // 0..15
    const int nt  = blockIdx.x & 31;     // 0..31
    const int l   = tid & 7;             // lane within pair
    const int nn  = (tid >> 3) & 3;      // n sub-slot
    const int bb  = tid >> 5;            // 0..7
    const int b   = bt * 8 + bb;
    const int nbase = nt * 64;

    float4 sacc[4][4];
#pragma unroll
    for (int j = 0; j < 4; ++j)
#pragma unroll
        for (int q = 0; q < 4; ++q) sacc[j][q] = make_float4(0.f, 0.f, 0.f, 0.f);

    // hoist v (routing vector) into registers: v[b, o=l+8j, d]
    float4 vr[4][4];
    if (!FIRST) {
        const float4* v4 = (const float4*)vin;
#pragma unroll
        for (int j = 0; j < 4; ++j) {
            const int o = l + 8 * j;
#pragma unroll
            for (int q = 0; q < 4; ++q)
                vr[j][q] = v4[b * 128 + o * 4 + q];
        }
    }

    const float4* Wg4 = (const float4*)Wg;

#pragma unroll 1
    for (int k = 0; k < 16; ++k) {
        __syncthreads();
        // stage W for n = nbase + 4k .. +3  (4096 float4 units, 16 per thread)
        {
            const int n0 = nbase + k * 4;
#pragma unroll
            for (int q = 0; q < 16; ++q) {
                const int u = tid + 256 * q;   // 0..4095
                const int r = u >> 5;          // 0..127 = nn_r*32 + o
                const int c = u & 31;
                const int n = n0 + (r >> 5);
                const int o = r & 31;
                Wl[r * 32 + (c ^ (r & 7))] = Wg4[(n * 32 + o) * 32 + c];
            }
        }
        __syncthreads();

        const int n = nbase + k * 4 + nn;
        const float4* xp = (const float4*)xg + (size_t)(b * NC + n) * 2;
        const float4 xa = xp[0];
        const float4 xb = xp[1];
        const float xs[8] = {xa.x, xa.y, xa.z, xa.w, xb.x, xb.y, xb.z, xb.w};

        // u_hat[o = l+8j][d = 4q+e]
        float4 u4[4][4];
#pragma unroll
        for (int j = 0; j < 4; ++j)
#pragma unroll
            for (int q = 0; q < 4; ++q) u4[j][q] = make_float4(0.f, 0.f, 0.f, 0.f);

#pragma unroll
        for (int j = 0; j < 4; ++j) {
            const int r = nn * 32 + l + 8 * j;   // r & 7 == l
            const float4* wrow = &Wl[r * 32];
#pragma unroll
            for (int i = 0; i < 8; ++i) {
#pragma unroll
                for (int q = 0; q < 4; ++q) {
                    const float4 w = wrow[(i * 4 + q) ^ l];
                    u4[j][q].x = fmaf(xs[i], w.x, u4[j][q].x);
                    u4[j][q].y = fmaf(xs[i], w.y, u4[j][q].y);
                    u4[j][q].z = fmaf(xs[i], w.z, u4[j][q].z);
                    u4[j][q].w = fmaf(xs[i], w.w, u4[j][q].w);
                }
            }
        }

        if (FIRST) {
            // c = softmax(0) = 1/32 uniform; scale applied once at the atomic.
#pragma unroll
            for (int j = 0; j < 4; ++j)
#pragma unroll
                for (int q = 0; q < 4; ++q) {
                    sacc[j][q].x += u4[j][q].x;
                    sacc[j][q].y += u4[j][q].y;
                    sacc[j][q].z += u4[j][q].z;
                    sacc[j][q].w += u4[j][q].w;
                }
        } else {
            // logits t[j] = sum_d u_hat[o][d] * v[b][o][d]
            float t[4];
#pragma unroll
            for (int j = 0; j < 4; ++j) {
                float acc = 0.f;
#pragma unroll
                for (int q = 0; q < 4; ++q) {
                    acc = fmaf(u4[j][q].x, vr[j][q].x, acc);
                    acc = fmaf(u4[j][q].y, vr[j][q].y, acc);
                    acc = fmaf(u4[j][q].z, vr[j][q].z, acc);
                    acc = fmaf(u4[j][q].w, vr[j][q].w, acc);
                }
                t[j] = acc;
            }
            // softmax over 32 o spread across 8 lanes (masks 1,2,4)
            float m = fmaxf(fmaxf(t[0], t[1]), fmaxf(t[2], t[3]));
            m = fmaxf(m, __shfl_xor(m, 1));
            m = fmaxf(m, __shfl_xor(m, 2));
            m = fmaxf(m, __shfl_xor(m, 4));
            float e[4];
            float Z = 0.f;
#pragma unroll
            for (int j = 0; j < 4; ++j) { e[j] = __expf(t[j] - m); Z += e[j]; }
            Z += __shfl_xor(Z, 1);
            Z += __shfl_xor(Z, 2);
            Z += __shfl_xor(Z, 4);
            const float inv = 1.0f / Z;
#pragma unroll
            for (int j = 0; j < 4; ++j) {
                const float c = e[j] * inv;
#pragma unroll
                for (int q = 0; q < 4; ++q) {
                    sacc[j][q].x = fmaf(c, u4[j][q].x, sacc[j][q].x);
                    sacc[j][q].y = fmaf(c, u4[j][q].y, sacc[j][q].y);
                    sacc[j][q].z = fmaf(c, u4[j][q].z, sacc[j][q].z);
                    sacc[j][q].w = fmaf(c, u4[j][q].w, sacc[j][q].w);
                }
            }
        }
    }

    // reduce the 4 n-sub-slots (masks 8 = nn^1, 16 = nn^2)
#pragma unroll
    for (int j = 0; j < 4; ++j)
#pragma unroll
        for (int q = 0; q < 4; ++q) {
            sacc[j][q].x += __shfl_xor(sacc[j][q].x, 8);
            sacc[j][q].y += __shfl_xor(sacc[j][q].y, 8);
            sacc[j][q].z += __shfl_xor(sacc[j][q].z, 8);
            sacc[j][q].w += __shfl_xor(sacc[j][q].w, 8);
            sacc[j][q].x += __shfl_xor(sacc[j][q].x, 16);
            sacc[j][q].y += __shfl_xor(sacc[j][q].y, 16);
            sacc[j][q].z += __shfl_xor(sacc[j][q].z, 16);
            sacc[j][q].w += __shfl_xor(sacc[j][q].w, 16);
        }

    if (nn == 0) {
        const float sc = FIRST ? (1.0f / 32.0f) : 1.0f;
#pragma unroll
        for (int j = 0; j < 4; ++j) {
            const int o = l + 8 * j;
            float* sb = sout + b * (OC * OD) + o * OD;
#pragma unroll
            for (int q = 0; q < 4; ++q) {
                atomicAdd(sb + q * 4 + 0, sacc[j][q].x * sc);
                atomicAdd(sb + q * 4 + 1, sacc[j][q].y * sc);
                atomicAdd(sb + q * 4 + 2, sacc[j][q].z * sc);
                atomicAdd(sb + q * 4 + 3, sacc[j][q].w * sc);
            }
        }
    }
}

// squash over d for each (b,o) row; optionally add vprev (to build v0+v1).
__global__ void squash_k(const float* __restrict__ s, const float* __restrict__ vprev,
                         float* __restrict__ vout)
{
    const int row = blockIdx.x * blockDim.x + threadIdx.x;   // 0..4095 = b*32+o
    if (row >= 128 * 32) return;
    const float4* s4 = (const float4*)s;
    float4 t[4];
    float sq = 0.f;
#pragma unroll
    for (int q = 0; q < 4; ++q) {
        t[q] = s4[row * 4 + q];
        sq += t[q].x * t[q].x + t[q].y * t[q].y + t[q].z * t[q].z + t[q].w * t[q].w;
    }
    const float f = sq / ((1.0f + sq) * sqrtf(sq + 1e-8f));
    float4* o4 = (float4*)vout;
    if (vprev) {
        const float4* p4 = (const float4*)vprev;
#pragma unroll
        for (int q = 0; q < 4; ++q) {
            float4 p = p4[row * 4 + q];
            float4 r;
            r.x = fmaf(t[q].x, f, p.x);
            r.y = fmaf(t[q].y, f, p.y);
            r.z = fmaf(t[q].z, f, p.z);
            r.w = fmaf(t[q].w, f, p.w);
            o4[row * 4 + q] = r;
        }
    } else {
#pragma unroll
        for (int q = 0; q < 4; ++q) {
            float4 r;
            r.x = t[q].x * f; r.y = t[q].y * f; r.z = t[q].z * f; r.w = t[q].w * f;
            o4[row * 4 + q] = r;
        }
    }
}

extern "C" void kernel_launch(void* const* d_in, const int* in_sizes, int n_in,
                              void* d_out, int out_size, void* d_ws, size_t ws_size,
                              hipStream_t stream)
{
    const float* x = (const float*)d_in[0];
    const float* W = (const float*)d_in[1];
    float* s  = (float*)d_ws;            // 65536 f32
    float* v0 = s + 65536;               // 65536 f32
    float* vs = v0 + 65536;              // 65536 f32 (v0 + v1)
    float* out = (float*)d_out;

    const size_t sbytes = (size_t)65536 * sizeof(float);

    // iter 0: uniform coupling 1/32
    hipMemsetAsync(s, 0, sbytes, stream);
    caps_pass<true><<<dim3(512), dim3(256), 0, stream>>>(x, W, nullptr, s);
    squash_k<<<dim3(16), dim3(256), 0, stream>>>(s, nullptr, v0);

    // iter 1: logits = dot(u_hat, v0)
    hipMemsetAsync(s, 0, sbytes, stream);
    caps_pass<false><<<dim3(512), dim3(256), 0, stream>>>(x, W, v0, s);
    squash_k<<<dim3(16), dim3(256), 0, stream>>>(s, v0, vs);   // vs = v0 + v1

    // iter 2: logits = dot(u_hat, v0) + dot(u_hat, v1) = dot(u_hat, vs)
    hipMemsetAsync(s, 0, sbytes, stream);
    caps_pass<false><<<dim3(512), dim3(256), 0, stream>>>(x, W, vs, s);
    squash_k<<<dim3(16), dim3(256), 0, stream>>>(s, nullptr, out);
}